// Round 4
// baseline (9663.937 us; speedup 1.0000x reference)
//
#include <hip/hip_runtime.h>
#include <hip/hip_bf16.h>
#include <hip/hip_cooperative_groups.h>

namespace cg = cooperative_groups;

#define B_ 32
#define T_ 256
#define E_ 300
#define H_ 512
#define O_ 10
#define NSL 64   // h-slices per direction (8 h-indices each), 2*NSL blocks total

// ---------------- kernel 1: embedding gather + xg = x@W_ih^T + b_ih + b_hh --------
// xg layout: [dir][t][row 0..2047][b] as bf16, row = gate*512 + h
__global__ __launch_bounds__(256) void embed_xg_k(
    const int* __restrict__ tokens, const float* __restrict__ embed,
    const float* __restrict__ Wf, const float* __restrict__ bif, const float* __restrict__ bhf,
    const float* __restrict__ Wb, const float* __restrict__ bib, const float* __restrict__ bhb,
    __hip_bfloat16* __restrict__ xg)
{
  const int rt  = blockIdx.x;   // 16 row tiles of 128 rows
  const int t   = blockIdx.y;   // time
  const int dir = blockIdx.z;
  const float* __restrict__ W  = dir ? Wb : Wf;
  const float* __restrict__ bi = dir ? bib : bif;
  const float* __restrict__ bh = dir ? bhb : bhf;

  __shared__ int   tok_s[B_];
  __shared__ float x_lds[B_][301];   // pad 300->301: odd stride -> conflict-free
  const int tid = threadIdx.x;
  if (tid < B_) tok_s[tid] = tokens[tid * T_ + t];
  __syncthreads();
  for (int i = tid; i < B_ * E_; i += 256) {
    int b = i / E_, e = i - b * E_;
    x_lds[b][e] = embed[(size_t)tok_s[b] * E_ + e];
  }
  __syncthreads();

  const int rg = tid >> 5, b = tid & 31;
  const int rbase = rt * 128 + rg * 16;
  float acc[16];
  #pragma unroll
  for (int j = 0; j < 16; ++j) acc[j] = 0.f;
  for (int e = 0; e < E_; e += 4) {     // 300 % 4 == 0
    const float xv0 = x_lds[b][e + 0];
    const float xv1 = x_lds[b][e + 1];
    const float xv2 = x_lds[b][e + 2];
    const float xv3 = x_lds[b][e + 3];
    #pragma unroll
    for (int j = 0; j < 16; ++j) {
      const float4 w = *(const float4*)(W + (size_t)(rbase + j) * E_ + e);
      acc[j] += w.x * xv0 + w.y * xv1 + w.z * xv2 + w.w * xv3;
    }
  }
  const size_t obase = ((size_t)(dir * T_ + t) * 2048 + rbase) * B_ + b;
  #pragma unroll
  for (int j = 0; j < 16; ++j) {
    const float v = acc[j] + bi[rbase + j] + bh[rbase + j];
    xg[obase + (size_t)j * B_] = __float2bfloat16(v);
  }
}

// ---------------- kernel 2: cooperative bidirectional LSTM recurrence -------------
__device__ __forceinline__ float sigm(float x)    { return 1.f / (1.f + __expf(-x)); }
__device__ __forceinline__ float tanhfast(float x){ return 1.f - 2.f / (__expf(2.f * x) + 1.f); }

__global__ __launch_bounds__(256) void lstm_rec_k(
    const __hip_bfloat16* __restrict__ xg,
    const float* __restrict__ Whf, const float* __restrict__ Whb,
    float* __restrict__ hcomm, float* __restrict__ pooled)
{
  cg::grid_group grid = cg::this_grid();

  const int dir = blockIdx.x & 1;   // even/odd -> XCD-segregated directions
  const int sl  = blockIdx.x >> 1;  // h-slice 0..63
  const int hs  = sl * 8;           // first h-index of this slice
  const float* __restrict__ Wh = dir ? Whb : Whf;   // [2048][512]

  extern __shared__ float lds[];
  float* h_lds = lds;               // [512][32] = 64 KiB (whole dynamic LDS)
  float* g_lds = lds;               // ALIASES h_lds[0:1024]; safe: barrier after matvec

  const int tid  = threadIdx.x;
  const int lane = tid & 63, wv = tid >> 6;     // wave = gate (i,f,g,o)
  const int mb   = lane & 31, hp = lane >> 5;   // matvec: batch lane, h-half
  const int eb   = tid & 31,  eh = tid >> 5;    // elementwise: batch, local h (0..7)

  const float* __restrict__ Wr0 = Wh + (size_t)(wv * H_ + hs + hp * 4) * H_;
  float c_st = 0.f, pm = 0.f;

  for (int s = 0; s < T_; ++s) {
    const int tt = dir ? (T_ - 1 - s) : s;
    // prefetch xg for this step
    float xgv[4];
    #pragma unroll
    for (int g = 0; g < 4; ++g)
      xgv[g] = __bfloat162float(xg[((size_t)(dir * T_ + tt) * 2048 + g * H_ + hs + eh) * B_ + eb]);

    float acc0 = 0.f, acc1 = 0.f, acc2 = 0.f, acc3 = 0.f;
    if (s > 0) {
      // stage h(s-1) [512][32] into LDS; plain loads are safe: grid.sync()'s
      // acquire fence (buffer_inv) ran after the producers' release (wbl2).
      const float4* src =
          (const float4*)(hcomm + (size_t)(dir * T_ + (s - 1)) * (H_ * B_));
      float4* dst = (float4*)h_lds;
      #pragma unroll
      for (int i = 0; i < 16; ++i)
        dst[tid + i * 256] = src[tid + i * 256];   // 4096 float4 = 16384 floats
      __syncthreads();
      // matvec: 4 rows (this gate, h = hs+hp*4+j) x 512, batch = mb
      for (int k = 0; k < H_; k += 4) {
        const float hv0 = h_lds[(k + 0) * B_ + mb];
        const float hv1 = h_lds[(k + 1) * B_ + mb];
        const float hv2 = h_lds[(k + 2) * B_ + mb];
        const float hv3 = h_lds[(k + 3) * B_ + mb];
        const float4 w0 = *(const float4*)(Wr0 + k);
        const float4 w1 = *(const float4*)(Wr0 + H_ + k);
        const float4 w2 = *(const float4*)(Wr0 + 2 * H_ + k);
        const float4 w3 = *(const float4*)(Wr0 + 3 * H_ + k);
        acc0 += w0.x * hv0 + w0.y * hv1 + w0.z * hv2 + w0.w * hv3;
        acc1 += w1.x * hv0 + w1.y * hv1 + w1.z * hv2 + w1.w * hv3;
        acc2 += w2.x * hv0 + w2.y * hv1 + w2.z * hv2 + w2.w * hv3;
        acc3 += w3.x * hv0 + w3.y * hv1 + w3.z * hv2 + w3.w * hv3;
      }
      __syncthreads();   // everyone done READING h_lds before g_lds (alias) writes
    }
    // exchange gates: g_lds[gate][hx][b]  (aliases h_lds[0:1024])
    g_lds[(wv * 8 + hp * 4 + 0) * 32 + mb] = acc0;
    g_lds[(wv * 8 + hp * 4 + 1) * 32 + mb] = acc1;
    g_lds[(wv * 8 + hp * 4 + 2) * 32 + mb] = acc2;
    g_lds[(wv * 8 + hp * 4 + 3) * 32 + mb] = acc3;
    __syncthreads();
    // elementwise LSTM cell for (b=eb, h=hs+eh)
    const float gi = g_lds[(0 * 8 + eh) * 32 + eb] + xgv[0];
    const float gf = g_lds[(1 * 8 + eh) * 32 + eb] + xgv[1];
    const float gg = g_lds[(2 * 8 + eh) * 32 + eb] + xgv[2];
    const float go = g_lds[(3 * 8 + eh) * 32 + eb] + xgv[3];
    c_st = sigm(gf) * c_st + sigm(gi) * tanhfast(gg);
    const float h = sigm(go) * tanhfast(c_st);
    pm = fmaxf(pm, h);   // == max over t of relu(h)
    hcomm[(size_t)(dir * T_ + s) * (H_ * B_) + (hs + eh) * B_ + eb] = h;
    // grid-wide barrier: release (L2 writeback) + arrive/spin + acquire (L2 inv)
    grid.sync();
  }
  pooled[(size_t)eb * 1024 + dir * H_ + hs + eh] = pm;
}

// ---------------- kernel 3: hcomm [dir][s][k][b] -> rnn_out [t][b][dir*512+k] -----
__global__ __launch_bounds__(256) void finalize_k(
    const float* __restrict__ hcomm, float* __restrict__ rnn)
{
  const int t = blockIdx.x, dir = blockIdx.y;
  const int s = dir ? (T_ - 1 - t) : t;             // step that produced time t
  const float* __restrict__ src = hcomm + (size_t)(dir * T_ + s) * (H_ * B_);
  const int b = threadIdx.x >> 3, kq = threadIdx.x & 7;
  float* __restrict__ dst = rnn + ((size_t)t * B_ + b) * 1024 + dir * H_;
  #pragma unroll
  for (int j = 0; j < 16; ++j) {
    const int k = kq * 64 + j * 4;
    float4 v;
    v.x = src[(k + 0) * B_ + b];
    v.y = src[(k + 1) * B_ + b];
    v.z = src[(k + 2) * B_ + b];
    v.w = src[(k + 3) * B_ + b];
    *(float4*)(dst + k) = v;
  }
}

// ---------------- kernel 4: logits = pooled @ W_out^T + b_out ---------------------
__global__ __launch_bounds__(64) void logits_k(
    const float* __restrict__ pooled, const float* __restrict__ Wout,
    const float* __restrict__ bout, float* __restrict__ out)
{
  const int b = blockIdx.x, lane = threadIdx.x;
  float acc[O_];
  #pragma unroll
  for (int o = 0; o < O_; ++o) acc[o] = 0.f;
  for (int k = lane; k < 2 * H_; k += 64) {
    const float pv = pooled[(size_t)b * 1024 + k];
    #pragma unroll
    for (int o = 0; o < O_; ++o) acc[o] += pv * Wout[(size_t)o * 1024 + k];
  }
  #pragma unroll
  for (int o = 0; o < O_; ++o) {
    float v = acc[o];
    #pragma unroll
    for (int off = 32; off > 0; off >>= 1) v += __shfl_down(v, off);
    if (lane == 0) out[b * O_ + o] = v + bout[o];
  }
}

extern "C" void kernel_launch(void* const* d_in, const int* in_sizes, int n_in,
                              void* d_out, int out_size, void* d_ws, size_t ws_size,
                              hipStream_t stream)
{
  const int*   tokens = (const int*)d_in[0];
  const float* embed  = (const float*)d_in[1];
  const float* Wihf   = (const float*)d_in[2];
  const float* Whhf   = (const float*)d_in[3];
  const float* bihf   = (const float*)d_in[4];
  const float* bhhf   = (const float*)d_in[5];
  const float* Wihb   = (const float*)d_in[6];
  const float* Whhb   = (const float*)d_in[7];
  const float* bihb   = (const float*)d_in[8];
  const float* bhhb   = (const float*)d_in[9];
  const float* Wout   = (const float*)d_in[10];
  const float* bout   = (const float*)d_in[11];
  float* out = (float*)d_out;

  char* ws = (char*)d_ws;
  const size_t XG_BYTES = (size_t)2 * T_ * 2048 * B_ * 2;  // 67,108,864
  const size_t HC_BYTES = (size_t)2 * T_ * H_ * B_ * 4;    // 33,554,432
  const size_t PL_BYTES = (size_t)B_ * 1024 * 4;           //    131,072
  if (ws_size < XG_BYTES + HC_BYTES + PL_BYTES) return;

  __hip_bfloat16* xg     = (__hip_bfloat16*)ws;
  float*          hcomm  = (float*)(ws + XG_BYTES);
  float*          pooled = (float*)(ws + XG_BYTES + HC_BYTES);

  embed_xg_k<<<dim3(16, T_, 2), 256, 0, stream>>>(
      tokens, embed, Wihf, bihf, bhhf, Wihb, bihb, bhhb, xg);

  const int rec_lds = H_ * B_ * 4;   // 65,536 B (g_lds aliases h_lds)
  (void)hipFuncSetAttribute((const void*)lstm_rec_k,
                            hipFuncAttributeMaxDynamicSharedMemorySize, rec_lds);
  {
    const __hip_bfloat16* xg_c = xg;
    void* args[] = { (void*)&xg_c, (void*)&Whhf, (void*)&Whhb,
                     (void*)&hcomm, (void*)&pooled };
    (void)hipLaunchCooperativeKernel((const void*)lstm_rec_k,
                                     dim3(2 * NSL), dim3(256),
                                     args, rec_lds, stream);
  }

  finalize_k<<<dim3(T_, 2), 256, 0, stream>>>(hcomm, out + B_ * O_);
  logits_k<<<dim3(B_), 64, 0, stream>>>(pooled, Wout, bout, out);
}